// Round 1
// baseline (16438.852 us; speedup 1.0000x reference)
//
#include <hip/hip_runtime.h>

// Problem dims
#define BB 64
#define CC 64
#define HH 32
#define WW 32
#define NPIX (HH*WW)                 // 1024
#define NELEM (BB*CC*NPIX)           // 4194304
#define CIN 65                       // t-channel + 64

// ---------------------------------------------------------------------------
// conv3x3: in (implicit [B,65,32,32] with channel 0 == tval inside image,
// zero pad outside), w [64,65,3,3], bias [64] -> out [B,64,32,32]
// Block: (og coutgroup of 16, rt rowtile of 8, b). Threads 256 = 8 rows x 32 cols.
// ---------------------------------------------------------------------------
__global__ __launch_bounds__(256) void conv3x3_k(
    const float* __restrict__ in, const float* __restrict__ w,
    const float* __restrict__ bias, float* __restrict__ out, float tval)
{
    __shared__ float tile[16][10][34];   // 21760 B
    const int og = blockIdx.x;           // 0..3
    const int rt = blockIdx.y;           // 0..3
    const int b  = blockIdx.z;           // 0..63
    const int tx = threadIdx.x;
    const int px = tx & 31;              // col 0..31
    const int py = tx >> 5;              // row-in-tile 0..7
    const int orow = rt*8 + py;

    float acc[16];
#pragma unroll
    for (int o = 0; o < 16; ++o) acc[o] = bias[og*16 + o];

    for (int c0 = 0; c0 < CIN; c0 += 16) {
        const int cc = min(16, CIN - c0);
        // ---- stage input chunk into LDS (zero-filled halo) ----
        const int total = cc * 340;      // cc*10*34
        for (int i = tx; i < total; i += 256) {
            int c   = i / 340;
            int rem = i - c*340;
            int r   = rem / 34;
            int col = rem - r*34;
            int gr  = rt*8 + r - 1;
            int gc  = col - 1;
            float v = 0.f;
            if ((unsigned)gr < 32u && (unsigned)gc < 32u) {
                int ci = c0 + c;
                v = (ci == 0) ? tval
                              : in[((b*CC + (ci-1))*HH + gr)*WW + gc];
            }
            tile[c][r][col] = v;
        }
        __syncthreads();
        // ---- accumulate ----
        for (int c = 0; c < cc; ++c) {
            const float* wp = w + ((size_t)(og*16)*CIN + (c0 + c)) * 9;
#pragma unroll
            for (int ky = 0; ky < 3; ++ky) {
#pragma unroll
                for (int kx = 0; kx < 3; ++kx) {
                    float v = tile[c][py+ky][px+kx];
#pragma unroll
                    for (int o = 0; o < 16; ++o) {
                        acc[o] = fmaf(wp[(size_t)o*CIN*9 + ky*3 + kx], v, acc[o]);
                    }
                }
            }
        }
        __syncthreads();
    }
#pragma unroll
    for (int o = 0; o < 16; ++o) {
        out[((b*CC + og*16 + o)*HH + orow)*WW + px] = acc[o];
    }
}

// ---------------------------------------------------------------------------
// GroupNorm (32 groups over 64 ch -> 2 ch/group), optional ReLU, in-place OK.
// One block per (b, g): 2048 elements.
// ---------------------------------------------------------------------------
__global__ __launch_bounds__(256) void groupnorm_k(
    const float* __restrict__ in, const float* __restrict__ scale,
    const float* __restrict__ bias, float* __restrict__ out, int do_relu)
{
    const int bidx = blockIdx.x;
    const int b = bidx >> 5;
    const int g = bidx & 31;
    const int tx = threadIdx.x;
    const float* p = in + (size_t)(b*CC + g*2) * NPIX;
    float4 v0 = ((const float4*)p)[tx];        // channel 2g
    float4 v1 = ((const float4*)p)[256 + tx];  // channel 2g+1

    float s  = v0.x+v0.y+v0.z+v0.w + v1.x+v1.y+v1.z+v1.w;
    float ss = v0.x*v0.x+v0.y*v0.y+v0.z*v0.z+v0.w*v0.w
             + v1.x*v1.x+v1.y*v1.y+v1.z*v1.z+v1.w*v1.w;
#pragma unroll
    for (int off = 32; off > 0; off >>= 1) {
        s  += __shfl_down(s,  off);
        ss += __shfl_down(ss, off);
    }
    __shared__ float red[10];
    const int wave = tx >> 6;
    if ((tx & 63) == 0) { red[wave] = s; red[4+wave] = ss; }
    __syncthreads();
    if (tx == 0) {
        float S  = red[0]+red[1]+red[2]+red[3];
        float SS = red[4]+red[5]+red[6]+red[7];
        float mu  = S * (1.f/2048.f);
        float var = SS * (1.f/2048.f) - mu*mu;
        red[8] = mu;
        red[9] = rsqrtf(var + 1e-5f);
    }
    __syncthreads();
    const float mu = red[8], rstd = red[9];
    const float a0 = rstd * scale[g*2],   c0 = bias[g*2]   - mu*a0;
    const float a1 = rstd * scale[g*2+1], c1 = bias[g*2+1] - mu*a1;

    float4 r0, r1;
    r0.x = fmaf(v0.x, a0, c0); r0.y = fmaf(v0.y, a0, c0);
    r0.z = fmaf(v0.z, a0, c0); r0.w = fmaf(v0.w, a0, c0);
    r1.x = fmaf(v1.x, a1, c1); r1.y = fmaf(v1.y, a1, c1);
    r1.z = fmaf(v1.z, a1, c1); r1.w = fmaf(v1.w, a1, c1);
    if (do_relu) {
        r0.x = fmaxf(r0.x, 0.f); r0.y = fmaxf(r0.y, 0.f);
        r0.z = fmaxf(r0.z, 0.f); r0.w = fmaxf(r0.w, 0.f);
        r1.x = fmaxf(r1.x, 0.f); r1.y = fmaxf(r1.y, 0.f);
        r1.z = fmaxf(r1.z, 0.f); r1.w = fmaxf(r1.w, 0.f);
    }
    float* q = out + (size_t)(b*CC + g*2) * NPIX;
    ((float4*)q)[tx]       = r0;
    ((float4*)q)[256 + tx] = r1;
}

// ---------------------------------------------------------------------------
// dst = y + a1*k1 + ... (first nk terms). float4, in-place safe (dst==y OK).
// ---------------------------------------------------------------------------
__global__ __launch_bounds__(256) void combine_k(
    float* __restrict__ dst, const float* __restrict__ y,
    const float* __restrict__ k1, const float* __restrict__ k2,
    const float* __restrict__ k3, const float* __restrict__ k4,
    const float* __restrict__ k5, const float* __restrict__ k6,
    float a1, float a2, float a3, float a4, float a5, float a6, int nk)
{
    const int i = blockIdx.x * 256 + threadIdx.x;   // float4 index
    float4 r = ((const float4*)y)[i];
    if (nk >= 1) { float4 v = ((const float4*)k1)[i];
        r.x = fmaf(a1,v.x,r.x); r.y = fmaf(a1,v.y,r.y);
        r.z = fmaf(a1,v.z,r.z); r.w = fmaf(a1,v.w,r.w); }
    if (nk >= 2) { float4 v = ((const float4*)k2)[i];
        r.x = fmaf(a2,v.x,r.x); r.y = fmaf(a2,v.y,r.y);
        r.z = fmaf(a2,v.z,r.z); r.w = fmaf(a2,v.w,r.w); }
    if (nk >= 3) { float4 v = ((const float4*)k3)[i];
        r.x = fmaf(a3,v.x,r.x); r.y = fmaf(a3,v.y,r.y);
        r.z = fmaf(a3,v.z,r.z); r.w = fmaf(a3,v.w,r.w); }
    if (nk >= 4) { float4 v = ((const float4*)k4)[i];
        r.x = fmaf(a4,v.x,r.x); r.y = fmaf(a4,v.y,r.y);
        r.z = fmaf(a4,v.z,r.z); r.w = fmaf(a4,v.w,r.w); }
    if (nk >= 5) { float4 v = ((const float4*)k5)[i];
        r.x = fmaf(a5,v.x,r.x); r.y = fmaf(a5,v.y,r.y);
        r.z = fmaf(a5,v.z,r.z); r.w = fmaf(a5,v.w,r.w); }
    if (nk >= 6) { float4 v = ((const float4*)k6)[i];
        r.x = fmaf(a6,v.x,r.x); r.y = fmaf(a6,v.y,r.y);
        r.z = fmaf(a6,v.z,r.z); r.w = fmaf(a6,v.w,r.w); }
    ((float4*)dst)[i] = r;
}

// ---------------------------------------------------------------------------

static const double A_[5][5] = {
    {0.161, 0, 0, 0, 0},
    {-0.008480655492356989, 0.335480655492357, 0, 0, 0},
    {2.8971530571054935, -6.359448489975075, 4.3622954328695815, 0, 0},
    {5.325864828439257, -11.748883564062828, 7.4955393428898365, -0.09249506636175525, 0},
    {5.86145544294642, -12.92096931784711, 8.159367898576159, -0.071584973281401, -0.028269050394068383},
};
static const double B_[6] = {
    0.09646076681806523, 0.01, 0.4798896504144996,
    1.379008574103742, -3.290069515436081, 2.324710524099774,
};
static const double C_[5] = {0.161, 0.327, 0.9, 0.9800255409045097, 1.0};

extern "C" void kernel_launch(void* const* d_in, const int* in_sizes, int n_in,
                              void* d_out, int out_size, void* d_ws, size_t ws_size,
                              hipStream_t stream)
{
    const float* x   = (const float*)d_in[0];
    const float* c1w = (const float*)d_in[1];
    const float* c1b = (const float*)d_in[2];
    const float* g1s = (const float*)d_in[3];
    const float* g1b = (const float*)d_in[4];
    const float* c2w = (const float*)d_in[5];
    const float* c2b = (const float*)d_in[6];
    const float* g2s = (const float*)d_in[7];
    const float* g2b = (const float*)d_in[8];

    float* y   = (float*)d_out;
    float* ws  = (float*)d_ws;
    float* xin = ws;
    float* h   = ws + (size_t)NELEM;
    float* k[6];
    for (int i = 0; i < 6; ++i) k[i] = ws + (size_t)(2 + i) * NELEM;

    const double dt = 0.125;
    const float dtf = 0.125f;

    // y <- x
    hipMemcpyAsync(y, x, (size_t)NELEM * sizeof(float),
                   hipMemcpyDeviceToDevice, stream);

    const dim3 cgrid(4, 4, BB);

    for (int s = 0; s < 8; ++s) {
        const float t0 = dtf * (float)s;
        for (int j = 0; j < 6; ++j) {
            const float tj = (j == 0) ? t0 : t0 + (float)C_[j-1] * dtf;
            const float* src = y;
            if (j > 0) {
                float a[5] = {0,0,0,0,0};
                for (int i = 0; i < j; ++i) a[i] = (float)(A_[j-1][i] * dt);
                combine_k<<<NELEM/1024, 256, 0, stream>>>(
                    xin, y, k[0], k[1], k[2], k[3], k[4], nullptr,
                    a[0], a[1], a[2], a[3], a[4], 0.f, j);
                src = xin;
            }
            conv3x3_k<<<cgrid, 256, 0, stream>>>(src, c1w, c1b, h, tj);
            groupnorm_k<<<BB*32, 256, 0, stream>>>(h, g1s, g1b, h, 1);
            conv3x3_k<<<cgrid, 256, 0, stream>>>(h, c2w, c2b, k[j], tj);
            groupnorm_k<<<BB*32, 256, 0, stream>>>(k[j], g2s, g2b, k[j], 0);
        }
        combine_k<<<NELEM/1024, 256, 0, stream>>>(
            y, y, k[0], k[1], k[2], k[3], k[4], k[5],
            (float)(B_[0]*dt), (float)(B_[1]*dt), (float)(B_[2]*dt),
            (float)(B_[3]*dt), (float)(B_[4]*dt), (float)(B_[5]*dt), 6);
    }
}

// Round 2
// 3522.010 us; speedup vs baseline: 4.6675x; 4.6675x over previous
//
#include <hip/hip_runtime.h>

typedef __attribute__((ext_vector_type(8))) __bf16 bf16x8;
typedef __attribute__((ext_vector_type(4))) float f32x4;
typedef unsigned short u16;

#define BB 64
#define CC 64
#define HH 32
#define WW 32
#define NPIX (HH*WW)                 // 1024
#define NELEM (BB*CC*NPIX)           // 4194304

// LDS input layout: [type(hi/lo)][row 6][col 34][cin 64 + pad 8] bf16
#define PIXS  72                     // ushorts per pixel (64 cin + 8 pad) -> 144B
#define PLANE (6*34*PIXS)            // 14688 ushorts per type plane

__device__ __forceinline__ u16 bf16_rn(float x) {
    unsigned u = __float_as_uint(x);
    unsigned r = u + 0x7FFFu + ((u >> 16) & 1u);
    return (u16)(r >> 16);
}
__device__ __forceinline__ void split2(float x, u16& h, u16& l) {
    h = bf16_rn(x);
    float hf = __uint_as_float(((unsigned)h) << 16);
    l = bf16_rn(x - hf);
}

// ---------------------------------------------------------------------------
// Weight prep: w [64][65][3][3] fp32 -> fragment-ready hi/lo bf16.
// Layout (ushort units): tap*8192 + (((kc*4+mt)*2+ty)*64 + lane)*8
// Fragment: A[m=lane&15 -> cout=mt*16+m][k=(lane>>4)*8+j -> cin=kc*32+k]
// (cin skips the t-channel: w index cin+1)
// ---------------------------------------------------------------------------
__global__ __launch_bounds__(256) void prep_w_k(
    const float* __restrict__ w, u16* __restrict__ wt)
{
    int t = blockIdx.x*256 + threadIdx.x;
    if (t >= 9216) return;
    int lane = t & 63;
    int f = t >> 6;              // ((tap*2+kc)*4+mt)*2+ty
    int ty  = f & 1;
    int mt  = (f >> 1) & 3;
    int kc  = (f >> 3) & 1;
    int tap = f >> 4;            // 0..8
    int cout = mt*16 + (lane & 15);
    int quad = lane >> 4;
    u16 v[8];
#pragma unroll
    for (int j = 0; j < 8; ++j) {
        int cin = kc*32 + quad*8 + j;
        float x = w[((size_t)cout*65 + (cin+1))*9 + tap];
        u16 h, l; split2(x, h, l);
        v[j] = ty ? l : h;
    }
    u16* dst = wt + ((size_t)tap*8192 + (((kc*4+mt)*2+ty)*64 + lane)*8);
    *(ushort4*)(dst)     = make_ushort4(v[0], v[1], v[2], v[3]);
    *(ushort4*)(dst + 4) = make_ushort4(v[4], v[5], v[6], v[7]);
}

// ---------------------------------------------------------------------------
// Smap: t-channel conv map. smap[cout][y][x] = sum over valid taps of w[cout][0][dy][dx]
// ---------------------------------------------------------------------------
__global__ __launch_bounds__(256) void smap_k(
    const float* __restrict__ w, float* __restrict__ smap)
{
    int t = blockIdx.x*256 + threadIdx.x;   // 65536
    int cout = t >> 10;
    int pix = t & 1023;
    int y = pix >> 5, x = pix & 31;
    float s = 0.f;
#pragma unroll
    for (int dy = 0; dy < 3; ++dy)
#pragma unroll
        for (int dx = 0; dx < 3; ++dx) {
            int yy = y + dy - 1, xx = x + dx - 1;
            if ((unsigned)yy < 32u && (unsigned)xx < 32u)
                s += w[(size_t)cout*65*9 + dy*3 + dx];
        }
    smap[t] = s;
}

// ---------------------------------------------------------------------------
// MFMA conv3x3 (bf16 hi/lo split implicit GEMM).
// Grid: (rt 0..7, b 0..63). Block 256 thr = 4 waves; block tile: all 64 cout
// x (4 rows x 32 cols). Wave w handles output row rt*4+w (64 cout x 32 px).
// out = acc + bias[cout] + tval*smap[cout][y][x]
// ---------------------------------------------------------------------------
__global__ __launch_bounds__(256, 2) void conv_mfma_k(
    const float* __restrict__ in, const u16* __restrict__ wt,
    const float* __restrict__ smap, const float* __restrict__ bias,
    float* __restrict__ out, float tval)
{
    __shared__ u16 lds_in[2*PLANE];   // 58752 B
    __shared__ u16 lds_w[8192];       // 16384 B (one tap: hi+lo, kc=0,1)
    const int rt  = blockIdx.x;
    const int b   = blockIdx.y;
    const int tid = threadIdx.x;
    const int wv   = tid >> 6;
    const int lane = tid & 63;
    const int quad = lane >> 4;
    const int n15  = lane & 15;

    // ---- stage input once: 16 cin-quads x 6 rows x 34 cols, hi/lo split ----
    for (int u = tid; u < 3264; u += 256) {
        int col = u % 34;
        int t1  = u / 34;
        int r   = t1 % 6;
        int cq  = t1 / 6;
        int gr = rt*4 + r - 1;
        int gc = col - 1;
        bool ok = ((unsigned)gr < 32u) && ((unsigned)gc < 32u);
        const float* p = in + (((size_t)b*64 + cq*4)*32 + gr)*32 + gc;
        u16 h[4], l[4];
#pragma unroll
        for (int i = 0; i < 4; ++i) {
            float v = ok ? p[(size_t)i*1024] : 0.f;
            split2(v, h[i], l[i]);
        }
        int off = (r*34 + col)*PIXS + cq*4;
        *(ushort4*)&lds_in[off]         = make_ushort4(h[0], h[1], h[2], h[3]);
        *(ushort4*)&lds_in[off + PLANE] = make_ushort4(l[0], l[1], l[2], l[3]);
    }

    f32x4 acc[4][2] = {};
    const uint4* wsrc = (const uint4*)wt;

    for (int tap = 0; tap < 9; ++tap) {
        __syncthreads();
        // stage this tap's weight fragments (16 KB)
#pragma unroll
        for (int i = 0; i < 4; ++i)
            ((uint4*)lds_w)[i*256 + tid] = wsrc[tap*1024 + i*256 + tid];
        __syncthreads();

        const int dy = tap / 3;
        const int dx = tap - dy*3;
        const int rowoff = (wv + dy)*34 + dx;

#pragma unroll
        for (int kc = 0; kc < 2; ++kc) {
            bf16x8 A[4][2], Bf[2][2];
#pragma unroll
            for (int mt = 0; mt < 4; ++mt)
#pragma unroll
                for (int ty = 0; ty < 2; ++ty)
                    A[mt][ty] = *(const bf16x8*)&lds_w[(((kc*4+mt)*2+ty)*64 + lane)*8];
#pragma unroll
            for (int nt = 0; nt < 2; ++nt)
#pragma unroll
                for (int ty = 0; ty < 2; ++ty)
                    Bf[nt][ty] = *(const bf16x8*)
                        &lds_in[ty*PLANE + (rowoff + nt*16 + n15)*PIXS + kc*32 + quad*8];
#pragma unroll
            for (int mt = 0; mt < 4; ++mt)
#pragma unroll
                for (int nt = 0; nt < 2; ++nt) {
                    acc[mt][nt] = __builtin_amdgcn_mfma_f32_16x16x32_bf16(
                        A[mt][0], Bf[nt][0], acc[mt][nt], 0, 0, 0);
                    acc[mt][nt] = __builtin_amdgcn_mfma_f32_16x16x32_bf16(
                        A[mt][0], Bf[nt][1], acc[mt][nt], 0, 0, 0);
                    acc[mt][nt] = __builtin_amdgcn_mfma_f32_16x16x32_bf16(
                        A[mt][1], Bf[nt][0], acc[mt][nt], 0, 0, 0);
                }
        }
    }

    // ---- epilogue: C/D layout col=lane&15, row=quad*4+reg ----
    const int orow = rt*4 + wv;
#pragma unroll
    for (int mt = 0; mt < 4; ++mt) {
#pragma unroll
        for (int r = 0; r < 4; ++r) {
            int cout = mt*16 + quad*4 + r;
            float bs = bias[cout];
            const float* sp = smap + (size_t)cout*1024 + orow*32;
            float* op = out + (((size_t)b*64 + cout)*32 + orow)*32;
#pragma unroll
            for (int nt = 0; nt < 2; ++nt) {
                int col = nt*16 + n15;
                op[col] = acc[mt][nt][r] + bs + tval*sp[col];
            }
        }
    }
}

// ---------------------------------------------------------------------------
// GroupNorm (32 groups over 64 ch -> 2 ch/group), optional ReLU, in-place OK.
// ---------------------------------------------------------------------------
__global__ __launch_bounds__(256) void groupnorm_k(
    const float* __restrict__ in, const float* __restrict__ scale,
    const float* __restrict__ bias, float* __restrict__ out, int do_relu)
{
    const int bidx = blockIdx.x;
    const int b = bidx >> 5;
    const int g = bidx & 31;
    const int tx = threadIdx.x;
    const float* p = in + (size_t)(b*CC + g*2) * NPIX;
    float4 v0 = ((const float4*)p)[tx];
    float4 v1 = ((const float4*)p)[256 + tx];

    float s  = v0.x+v0.y+v0.z+v0.w + v1.x+v1.y+v1.z+v1.w;
    float ss = v0.x*v0.x+v0.y*v0.y+v0.z*v0.z+v0.w*v0.w
             + v1.x*v1.x+v1.y*v1.y+v1.z*v1.z+v1.w*v1.w;
#pragma unroll
    for (int off = 32; off > 0; off >>= 1) {
        s  += __shfl_down(s,  off);
        ss += __shfl_down(ss, off);
    }
    __shared__ float red[10];
    const int wave = tx >> 6;
    if ((tx & 63) == 0) { red[wave] = s; red[4+wave] = ss; }
    __syncthreads();
    if (tx == 0) {
        float S  = red[0]+red[1]+red[2]+red[3];
        float SS = red[4]+red[5]+red[6]+red[7];
        float mu  = S * (1.f/2048.f);
        float var = SS * (1.f/2048.f) - mu*mu;
        red[8] = mu;
        red[9] = rsqrtf(var + 1e-5f);
    }
    __syncthreads();
    const float mu = red[8], rstd = red[9];
    const float a0 = rstd * scale[g*2],   c0 = bias[g*2]   - mu*a0;
    const float a1 = rstd * scale[g*2+1], c1 = bias[g*2+1] - mu*a1;

    float4 r0, r1;
    r0.x = fmaf(v0.x, a0, c0); r0.y = fmaf(v0.y, a0, c0);
    r0.z = fmaf(v0.z, a0, c0); r0.w = fmaf(v0.w, a0, c0);
    r1.x = fmaf(v1.x, a1, c1); r1.y = fmaf(v1.y, a1, c1);
    r1.z = fmaf(v1.z, a1, c1); r1.w = fmaf(v1.w, a1, c1);
    if (do_relu) {
        r0.x = fmaxf(r0.x, 0.f); r0.y = fmaxf(r0.y, 0.f);
        r0.z = fmaxf(r0.z, 0.f); r0.w = fmaxf(r0.w, 0.f);
        r1.x = fmaxf(r1.x, 0.f); r1.y = fmaxf(r1.y, 0.f);
        r1.z = fmaxf(r1.z, 0.f); r1.w = fmaxf(r1.w, 0.f);
    }
    float* q = out + (size_t)(b*CC + g*2) * NPIX;
    ((float4*)q)[tx]       = r0;
    ((float4*)q)[256 + tx] = r1;
}

// ---------------------------------------------------------------------------
// dst = y + a1*k1 + ... (first nk terms). float4, in-place safe.
// ---------------------------------------------------------------------------
__global__ __launch_bounds__(256) void combine_k(
    float* __restrict__ dst, const float* __restrict__ y,
    const float* __restrict__ k1, const float* __restrict__ k2,
    const float* __restrict__ k3, const float* __restrict__ k4,
    const float* __restrict__ k5, const float* __restrict__ k6,
    float a1, float a2, float a3, float a4, float a5, float a6, int nk)
{
    const int i = blockIdx.x * 256 + threadIdx.x;
    float4 r = ((const float4*)y)[i];
    if (nk >= 1) { float4 v = ((const float4*)k1)[i];
        r.x = fmaf(a1,v.x,r.x); r.y = fmaf(a1,v.y,r.y);
        r.z = fmaf(a1,v.z,r.z); r.w = fmaf(a1,v.w,r.w); }
    if (nk >= 2) { float4 v = ((const float4*)k2)[i];
        r.x = fmaf(a2,v.x,r.x); r.y = fmaf(a2,v.y,r.y);
        r.z = fmaf(a2,v.z,r.z); r.w = fmaf(a2,v.w,r.w); }
    if (nk >= 3) { float4 v = ((const float4*)k3)[i];
        r.x = fmaf(a3,v.x,r.x); r.y = fmaf(a3,v.y,r.y);
        r.z = fmaf(a3,v.z,r.z); r.w = fmaf(a3,v.w,r.w); }
    if (nk >= 4) { float4 v = ((const float4*)k4)[i];
        r.x = fmaf(a4,v.x,r.x); r.y = fmaf(a4,v.y,r.y);
        r.z = fmaf(a4,v.z,r.z); r.w = fmaf(a4,v.w,r.w); }
    if (nk >= 5) { float4 v = ((const float4*)k5)[i];
        r.x = fmaf(a5,v.x,r.x); r.y = fmaf(a5,v.y,r.y);
        r.z = fmaf(a5,v.z,r.z); r.w = fmaf(a5,v.w,r.w); }
    if (nk >= 6) { float4 v = ((const float4*)k6)[i];
        r.x = fmaf(a6,v.x,r.x); r.y = fmaf(a6,v.y,r.y);
        r.z = fmaf(a6,v.z,r.z); r.w = fmaf(a6,v.w,r.w); }
    ((float4*)dst)[i] = r;
}

// ---------------------------------------------------------------------------

static const double A_[5][5] = {
    {0.161, 0, 0, 0, 0},
    {-0.008480655492356989, 0.335480655492357, 0, 0, 0},
    {2.8971530571054935, -6.359448489975075, 4.3622954328695815, 0, 0},
    {5.325864828439257, -11.748883564062828, 7.4955393428898365, -0.09249506636175525, 0},
    {5.86145544294642, -12.92096931784711, 8.159367898576159, -0.071584973281401, -0.028269050394068383},
};
static const double B_[6] = {
    0.09646076681806523, 0.01, 0.4798896504144996,
    1.379008574103742, -3.290069515436081, 2.324710524099774,
};
static const double C_[5] = {0.161, 0.327, 0.9, 0.9800255409045097, 1.0};

extern "C" void kernel_launch(void* const* d_in, const int* in_sizes, int n_in,
                              void* d_out, int out_size, void* d_ws, size_t ws_size,
                              hipStream_t stream)
{
    const float* x   = (const float*)d_in[0];
    const float* c1w = (const float*)d_in[1];
    const float* c1b = (const float*)d_in[2];
    const float* g1s = (const float*)d_in[3];
    const float* g1b = (const float*)d_in[4];
    const float* c2w = (const float*)d_in[5];
    const float* c2b = (const float*)d_in[6];
    const float* g2s = (const float*)d_in[7];
    const float* g2b = (const float*)d_in[8];

    float* y   = (float*)d_out;
    float* ws  = (float*)d_ws;
    float* xin = ws;
    float* h   = ws + (size_t)NELEM;
    float* k[6];
    for (int i = 0; i < 6; ++i) k[i] = ws + (size_t)(2 + i) * NELEM;
    u16*   wt1   = (u16*)(ws + (size_t)8*NELEM);
    u16*   wt2   = wt1 + 73728;
    float* smap1 = (float*)(wt2 + 73728);
    float* smap2 = smap1 + 65536;

    const double dt = 0.125;
    const float dtf = 0.125f;

    // one-time (per launch) weight transforms
    prep_w_k<<<36, 256, 0, stream>>>(c1w, wt1);
    prep_w_k<<<36, 256, 0, stream>>>(c2w, wt2);
    smap_k<<<256, 256, 0, stream>>>(c1w, smap1);
    smap_k<<<256, 256, 0, stream>>>(c2w, smap2);

    // y <- x
    hipMemcpyAsync(y, x, (size_t)NELEM * sizeof(float),
                   hipMemcpyDeviceToDevice, stream);

    const dim3 cgrid(8, BB);

    for (int s = 0; s < 8; ++s) {
        const float t0 = dtf * (float)s;
        for (int j = 0; j < 6; ++j) {
            const float tj = (j == 0) ? t0 : t0 + (float)C_[j-1] * dtf;
            const float* src = y;
            if (j > 0) {
                float a[5] = {0,0,0,0,0};
                for (int i = 0; i < j; ++i) a[i] = (float)(A_[j-1][i] * dt);
                combine_k<<<NELEM/1024, 256, 0, stream>>>(
                    xin, y, k[0], k[1], k[2], k[3], k[4], nullptr,
                    a[0], a[1], a[2], a[3], a[4], 0.f, j);
                src = xin;
            }
            conv_mfma_k<<<cgrid, 256, 0, stream>>>(src, wt1, smap1, c1b, h, tj);
            groupnorm_k<<<BB*32, 256, 0, stream>>>(h, g1s, g1b, h, 1);
            conv_mfma_k<<<cgrid, 256, 0, stream>>>(h, wt2, smap2, c2b, k[j], tj);
            groupnorm_k<<<BB*32, 256, 0, stream>>>(k[j], g2s, g2b, k[j], 0);
        }
        combine_k<<<NELEM/1024, 256, 0, stream>>>(
            y, y, k[0], k[1], k[2], k[3], k[4], k[5],
            (float)(B_[0]*dt), (float)(B_[1]*dt), (float)(B_[2]*dt),
            (float)(B_[3]*dt), (float)(B_[4]*dt), (float)(B_[5]*dt), 6);
    }
}